// Round 7
// baseline (802.892 us; speedup 1.0000x reference)
//
#include <hip/hip_runtime.h>

#define BATCH 8
#define NPTS 4096
#define KSAMP 1024
#define KNEI 64
#define OUTC 131   // 3 xyz + 128 feat

typedef __attribute__((ext_vector_type(8))) short  bf16x8;
typedef __attribute__((ext_vector_type(4))) float  f32x4;

// ---------------------------------------------------------------------------
// bf16 split helpers (RNE via bit arithmetic; exact).
// a ~= bf2f(hi) + bf2f(lo) with relative error ~2^-17.
// ---------------------------------------------------------------------------
__device__ __forceinline__ unsigned short f2bf_rne(float f)
{
    unsigned u = __float_as_uint(f);
    return (unsigned short)((u + 0x7FFFu + ((u >> 16) & 1u)) >> 16);
}
__device__ __forceinline__ float bf2f(unsigned short h)
{
    return __uint_as_float(((unsigned)h) << 16);
}

// ---------------------------------------------------------------------------
// DPP wave64 reductions (verified R2+). Result valid in lane 63.
// ---------------------------------------------------------------------------
__device__ __forceinline__ unsigned long long umax64(unsigned long long a,
                                                     unsigned long long b)
{
    return a > b ? a : b;
}

#define DPP_U64_STEP(v, CTRL)                                                  \
    {                                                                          \
        int _lo = __builtin_amdgcn_update_dpp(0, (int)(unsigned)(v), (CTRL),   \
                                              0xF, 0xF, true);                 \
        int _hi = __builtin_amdgcn_update_dpp(0, (int)((v) >> 32), (CTRL),     \
                                              0xF, 0xF, true);                 \
        unsigned long long _o =                                                \
            ((unsigned long long)(unsigned)_hi << 32) | (unsigned)_lo;         \
        (v) = umax64((v), _o);                                                 \
    }

__device__ __forceinline__ unsigned long long wave_umax64(unsigned long long v)
{
    DPP_U64_STEP(v, 0x111)
    DPP_U64_STEP(v, 0x112)
    DPP_U64_STEP(v, 0x114)
    DPP_U64_STEP(v, 0x118)
    DPP_U64_STEP(v, 0x142)
    DPP_U64_STEP(v, 0x143)
    return v;
}

#define DPP_F32MAX_STEP(v, CTRL)                                               \
    {                                                                          \
        int _s = __builtin_amdgcn_update_dpp(0, __float_as_int(v), (CTRL),     \
                                             0xF, 0xF, true);                  \
        (v) = fmaxf((v), __int_as_float(_s));                                  \
    }

__device__ __forceinline__ float wave_fmax_nonneg(float v)
{
    DPP_F32MAX_STEP(v, 0x111)
    DPP_F32MAX_STEP(v, 0x112)
    DPP_F32MAX_STEP(v, 0x114)
    DPP_F32MAX_STEP(v, 0x118)
    DPP_F32MAX_STEP(v, 0x142)
    DPP_F32MAX_STEP(v, 0x143)
    return v;
}

// ---------------------------------------------------------------------------
// Kernel 1: FPS. Structure and selection semantics FROZEN from the verified
// R2 kernel; only the thread geometry changes: 512 threads (8 waves -> 2
// waves/SIMD) x 8 pts/thread. Rationale: at 1 wave/SIMD every dependent
// cmp/cndmask chain pays full latency; a second wave per SIMD interleaves
// and hides it. Total VALU work per SIMD is ~unchanged. Index mapping stays
// thread-ascending (n = t*8+i), so the u64 key tie-break is bit-exact.
// ---------------------------------------------------------------------------
#define FPS_T 512
#define FPS_PPT 8
#define FPS_NW (FPS_T / 64)

__global__ __launch_bounds__(FPS_T) void fps_kernel(const float* __restrict__ pts,
                                                    float* __restrict__ out)
{
    const int b = blockIdx.x;
    const int t = threadIdx.x;
    const float* p = pts + (size_t)b * NPTS * 3;

    __shared__ float lx[NPTS], ly[NPTS], lz[NPTS];
    __shared__ unsigned long long cand[2][FPS_NW];

    float px[FPS_PPT], py[FPS_PPT], pz[FPS_PPT], md[FPS_PPT];
#pragma unroll
    for (int i = 0; i < FPS_PPT; ++i) {
        const int n = t * FPS_PPT + i;
        px[i] = p[n * 3 + 0];
        py[i] = p[n * 3 + 1];
        pz[i] = p[n * 3 + 2];
        lx[n] = px[i]; ly[n] = py[i]; lz[n] = pz[i];
        md[i] = 1e10f;                   // reference 'big'
    }
    if (t == 0) {
        float* o = out + (size_t)b * KSAMP * OUTC;
        o[0] = p[0]; o[1] = p[1]; o[2] = p[2];   // first selected = index 0
    }
    __syncthreads();

    const int wave = t >> 6;
    const int lane = t & 63;
    int cur = 0;

    for (int s = 1; s < KSAMP; ++s) {
        const float qx = lx[cur], qy = ly[cur], qz = lz[cur];

        // min-dist update: op sequence FROZEN (sub,sub,sub,mul,fma,fma,min)
#pragma unroll
        for (int i = 0; i < FPS_PPT; ++i) {
            float dx = px[i] - qx, dy = py[i] - qy, dz = pz[i] - qz;
            float d = dx * dx + dy * dy + dz * dz;
            md[i] = fminf(md[i], d);
        }

        // thread-local tree argmax over packed candidates (exact tie-break)
        unsigned long long c[FPS_PPT];
#pragma unroll
        for (int i = 0; i < FPS_PPT; ++i)
            c[i] = ((unsigned long long)__float_as_uint(md[i]) << 32)
                 | (unsigned)(4095 - (t * FPS_PPT + i));
#pragma unroll
        for (int i = 0; i < 4; ++i) c[i] = umax64(c[i], c[i + 4]);
        c[0] = umax64(c[0], c[2]);
        c[1] = umax64(c[1], c[3]);
        unsigned long long best = umax64(c[0], c[1]);

        best = wave_umax64(best);
        const int par = s & 1;
        if (lane == 63) cand[par][wave] = best;
        __syncthreads();

        // 8-candidate pairwise tree (keys are globally unique -> exact)
        const unsigned long long g01 = umax64(cand[par][0], cand[par][1]);
        const unsigned long long g23 = umax64(cand[par][2], cand[par][3]);
        const unsigned long long g45 = umax64(cand[par][4], cand[par][5]);
        const unsigned long long g67 = umax64(cand[par][6], cand[par][7]);
        const unsigned long long g = umax64(umax64(g01, g23), umax64(g45, g67));
        cur = 4095 - (int)(g & 0xffffffffu);

        if (t == 0) {
            float* o = out + ((size_t)b * KSAMP + s) * OUTC;
            o[0] = lx[cur]; o[1] = ly[cur]; o[2] = lz[cur];
        }
    }
}

// ---------------------------------------------------------------------------
// Weight prep (verified R6): split w1/w2 into bf16 hi/lo in MFMA B-frag
// order. ws layout (ushort units): B1hi @0, B1lo @4096, B2hi @8192,
// B2lo @16384. Total 49152 bytes.
// ---------------------------------------------------------------------------
__global__ __launch_bounds__(256) void prep_kernel(const float* __restrict__ w1,
                                                   const float* __restrict__ w2,
                                                   unsigned short* __restrict__ ws)
{
    const int tid = blockIdx.x * 256 + threadIdx.x;
    if (tid >= 1536) return;
    const int fid  = tid >> 6;
    const int lane = tid & 63;
    const int lg = lane >> 4, lr = lane & 15;

    const float* W; int N, f; unsigned base_hi, base_lo;
    if (fid < 8) { W = w1; N = 64;  f = fid;     base_hi = 0;    base_lo = 4096; }
    else         { W = w2; N = 128; f = fid - 8; base_hi = 8192; base_lo = 16384; }
    const int nt = f >> 1, kc = f & 1;
    const int col = nt * 16 + lr;

    bf16x8 hi8, lo8;
#pragma unroll
    for (int i = 0; i < 8; ++i) {
        const int k = kc * 32 + lg * 8 + i;
        const float w = W[k * N + col];
        const unsigned short hs = f2bf_rne(w);
        hi8[i] = (short)hs;
        lo8[i] = (short)f2bf_rne(w - bf2f(hs));
    }
    ((bf16x8*)(ws + base_hi))[f * 64 + lane] = hi8;
    ((bf16x8*)(ws + base_lo))[f * 64 + lane] = lo8;
}

// ---------------------------------------------------------------------------
// Kernel 2 (MFMA, verified R6): ball-query + L1 fp32 (frozen numerics) +
// L2/L3 3-pass bf16-split MFMA + fused relu/max-pool. One change vs R6: the
// ball-query loop no longer early-exits on total>=KNEI, so chunk loads are
// control-independent and software-pipelined (prefetch next chunk). The
// insert guard pos<KNEI alone produces identical inserts (first 64 in index
// order) -> output provably unchanged.
// ---------------------------------------------------------------------------
#define HPAD 72

__global__ __launch_bounds__(64) void bqmlp_mfma(
    const float* __restrict__ pts,
    const float* __restrict__ w0, const float* __restrict__ b0,
    const float* __restrict__ b1, const float* __restrict__ b2,
    const unsigned short* __restrict__ ws,
    float* __restrict__ out)
{
    const int q    = blockIdx.x;        // 0..8191
    const int bb   = q >> 10;
    const int lane = threadIdx.x;
    const int lg   = lane >> 4, lr = lane & 15;
    const float* p = pts + (size_t)bb * NPTS * 3;
    float* orow    = out + (size_t)q * OUTC;

    __shared__ unsigned short hb_hi[64 * HPAD];
    __shared__ unsigned short hb_lo[64 * HPAD];
    __shared__ float snx[KNEI], sny[KNEI], snz[KNEI];

    // ---- ball query (FROZEN comparison numerics) ----
    const float qx = orow[0], qy = orow[1], qz = orow[2];
    const float RR = 0.04f;
    const float q2 = __fadd_rn(__fadd_rn(__fmul_rn(qx, qx), __fmul_rn(qy, qy)),
                               __fmul_rn(qz, qz));

    snx[lane] = 0.0f; sny[lane] = 0.0f; snz[lane] = 0.0f;
    __syncthreads();

    // prefetch chunk 0
    float cx = p[lane * 3 + 0];
    float cy = p[lane * 3 + 1];
    float cz = p[lane * 3 + 2];

    int total = 0;
#pragma unroll 4
    for (int c = 0; c < NPTS / 64; ++c) {
        const float x = cx, y = cy, z = cz;
        if (c + 1 < NPTS / 64) {
            const int n2 = (c + 1) * 64 + lane;
            cx = p[n2 * 3 + 0];
            cy = p[n2 * 3 + 1];
            cz = p[n2 * 3 + 2];
        }
        const float p2  = __fadd_rn(__fadd_rn(__fmul_rn(x, x), __fmul_rn(y, y)),
                                    __fmul_rn(z, z));
        const float dot = __fadd_rn(__fadd_rn(__fmul_rn(qx, x), __fmul_rn(qy, y)),
                                    __fmul_rn(qz, z));
        const float d2  = __fsub_rn(__fadd_rn(q2, p2), __fmul_rn(2.0f, dot));
        const bool valid = d2 < RR;
        const unsigned long long mask = __ballot(valid);
        const int pos = total + (int)__popcll(mask & ((1ull << lane) - 1ull));
        if (valid && pos < KNEI) { snx[pos] = x; sny[pos] = y; snz[pos] = z; }
        total += (int)__popcll(mask);
    }
    __syncthreads();

    const float x = snx[lane], y = sny[lane], z = snz[lane];

    // ---- layer 1: 3 -> 64, fp32 (FROZEN numerics), lane = neighbor ----
    float h0[64];
#pragma unroll
    for (int j = 0; j < 64; ++j) {
        float a = fmaf(x, w0[j], fmaf(y, w0[64 + j], fmaf(z, w0[128 + j], b0[j])));
        h0[j] = fmaxf(a, 0.0f);
    }

    // ---- split h0 -> LDS bf16 hi/lo rows (lane = row) ----
#pragma unroll
    for (int c = 0; c < 8; ++c) {
        bf16x8 hi8, lo8;
#pragma unroll
        for (int i = 0; i < 8; ++i) {
            const float v = h0[c * 8 + i];
            const unsigned short hs = f2bf_rne(v);
            hi8[i] = (short)hs;
            lo8[i] = (short)f2bf_rne(v - bf2f(hs));
        }
        *(bf16x8*)&hb_hi[lane * HPAD + c * 8] = hi8;
        *(bf16x8*)&hb_lo[lane * HPAD + c * 8] = lo8;
    }
    __syncthreads();

    const bf16x8* B1h = (const bf16x8*)ws;          // entries [f*64+lane]
    const bf16x8* B1l = B1h + 512;
    const bf16x8* B2h = B1h + 1024;
    const bf16x8* B2l = B1h + 2048;

    // ---- layer 2: 64 -> 64 via MFMA ----
    f32x4 acc2[4][4];
#pragma unroll
    for (int nt = 0; nt < 4; ++nt) {
        const float bv = b1[nt * 16 + lr];
#pragma unroll
        for (int mt = 0; mt < 4; ++mt)
            acc2[mt][nt] = (f32x4){bv, bv, bv, bv};
    }

#pragma unroll
    for (int mt = 0; mt < 4; ++mt) {
        bf16x8 ah[2], al[2];
#pragma unroll
        for (int kc = 0; kc < 2; ++kc) {
            ah[kc] = *(const bf16x8*)&hb_hi[(mt * 16 + lr) * HPAD + kc * 32 + lg * 8];
            al[kc] = *(const bf16x8*)&hb_lo[(mt * 16 + lr) * HPAD + kc * 32 + lg * 8];
        }
#pragma unroll
        for (int nt = 0; nt < 4; ++nt) {
#pragma unroll
            for (int kc = 0; kc < 2; ++kc) {
                const bf16x8 bh = B1h[(nt * 2 + kc) * 64 + lane];
                const bf16x8 bl = B1l[(nt * 2 + kc) * 64 + lane];
                acc2[mt][nt] = __builtin_amdgcn_mfma_f32_16x16x32_bf16(ah[kc], bh, acc2[mt][nt], 0, 0, 0);
                acc2[mt][nt] = __builtin_amdgcn_mfma_f32_16x16x32_bf16(ah[kc], bl, acc2[mt][nt], 0, 0, 0);
                acc2[mt][nt] = __builtin_amdgcn_mfma_f32_16x16x32_bf16(al[kc], bh, acc2[mt][nt], 0, 0, 0);
            }
        }
    }

    // ---- relu + split h1 -> LDS (C layout: row = mt*16+4*lg+r, col = nt*16+lr) ----
    __syncthreads();
#pragma unroll
    for (int mt = 0; mt < 4; ++mt) {
#pragma unroll
        for (int nt = 0; nt < 4; ++nt) {
#pragma unroll
            for (int r = 0; r < 4; ++r) {
                const float v = fmaxf(acc2[mt][nt][r], 0.0f);
                const int row = mt * 16 + lg * 4 + r;
                const int col = nt * 16 + lr;
                const unsigned short hs = f2bf_rne(v);
                hb_hi[row * HPAD + col] = hs;
                hb_lo[row * HPAD + col] = f2bf_rne(v - bf2f(hs));
            }
        }
    }
    __syncthreads();

    // ---- layer 3: 64 -> 128 via MFMA; fused relu+pool ----
#pragma unroll
    for (int h = 0; h < 2; ++h) {
        f32x4 acc3[4][4];
#pragma unroll
        for (int nt4 = 0; nt4 < 4; ++nt4) {
            const float bv = b2[(h * 4 + nt4) * 16 + lr];
#pragma unroll
            for (int mt = 0; mt < 4; ++mt)
                acc3[mt][nt4] = (f32x4){bv, bv, bv, bv};
        }

#pragma unroll
        for (int mt = 0; mt < 4; ++mt) {
            bf16x8 ah[2], al[2];
#pragma unroll
            for (int kc = 0; kc < 2; ++kc) {
                ah[kc] = *(const bf16x8*)&hb_hi[(mt * 16 + lr) * HPAD + kc * 32 + lg * 8];
                al[kc] = *(const bf16x8*)&hb_lo[(mt * 16 + lr) * HPAD + kc * 32 + lg * 8];
            }
#pragma unroll
            for (int nt4 = 0; nt4 < 4; ++nt4) {
                const int f = (h * 4 + nt4) * 2;
#pragma unroll
                for (int kc = 0; kc < 2; ++kc) {
                    const bf16x8 bh = B2h[(f + kc) * 64 + lane];
                    const bf16x8 bl = B2l[(f + kc) * 64 + lane];
                    acc3[mt][nt4] = __builtin_amdgcn_mfma_f32_16x16x32_bf16(ah[kc], bh, acc3[mt][nt4], 0, 0, 0);
                    acc3[mt][nt4] = __builtin_amdgcn_mfma_f32_16x16x32_bf16(ah[kc], bl, acc3[mt][nt4], 0, 0, 0);
                    acc3[mt][nt4] = __builtin_amdgcn_mfma_f32_16x16x32_bf16(al[kc], bh, acc3[mt][nt4], 0, 0, 0);
                }
            }
        }

#pragma unroll
        for (int nt4 = 0; nt4 < 4; ++nt4) {
            float m = 0.0f;   // max(relu(.)) == relu(max(.)), identity 0 exact
#pragma unroll
            for (int mt = 0; mt < 4; ++mt)
#pragma unroll
                for (int r = 0; r < 4; ++r)
                    m = fmaxf(m, acc3[mt][nt4][r]);
            m = fmaxf(m, __shfl_xor(m, 16));
            m = fmaxf(m, __shfl_xor(m, 32));
            if (lane < 16) orow[3 + (h * 4 + nt4) * 16 + lane] = m;
        }
    }
}

// ---------------------------------------------------------------------------
// Fallback fp32 MLP kernel (R1/R2-verified), used only if ws_size is too
// small for the weight prep buffer.
// ---------------------------------------------------------------------------
__global__ __launch_bounds__(64) void bqmlp_fp32(
    const float* __restrict__ pts,
    const float* __restrict__ w0, const float* __restrict__ b0,
    const float* __restrict__ w1, const float* __restrict__ b1,
    const float* __restrict__ w2, const float* __restrict__ b2,
    float* __restrict__ out)
{
    const int q    = blockIdx.x;
    const int bb   = q >> 10;
    const int lane = threadIdx.x;
    const float* p = pts + (size_t)bb * NPTS * 3;
    float* orow    = out + (size_t)q * OUTC;

    const float qx = orow[0], qy = orow[1], qz = orow[2];
    const float RR = 0.04f;
    const float q2 = __fadd_rn(__fadd_rn(__fmul_rn(qx, qx), __fmul_rn(qy, qy)),
                               __fmul_rn(qz, qz));

    __shared__ float nx[KNEI], ny[KNEI], nz[KNEI];
    nx[lane] = 0.0f; ny[lane] = 0.0f; nz[lane] = 0.0f;
    __syncthreads();

    int total = 0;
    for (int c = 0; c < NPTS / 64 && total < KNEI; ++c) {
        const int n = c * 64 + lane;
        const float x = p[n * 3 + 0];
        const float y = p[n * 3 + 1];
        const float z = p[n * 3 + 2];
        const float p2  = __fadd_rn(__fadd_rn(__fmul_rn(x, x), __fmul_rn(y, y)),
                                    __fmul_rn(z, z));
        const float dot = __fadd_rn(__fadd_rn(__fmul_rn(qx, x), __fmul_rn(qy, y)),
                                    __fmul_rn(qz, z));
        const float d2  = __fsub_rn(__fadd_rn(q2, p2), __fmul_rn(2.0f, dot));
        const bool valid = d2 < RR;
        const unsigned long long mask = __ballot(valid);
        const int pos = total + (int)__popcll(mask & ((1ull << lane) - 1ull));
        if (valid && pos < KNEI) { nx[pos] = x; ny[pos] = y; nz[pos] = z; }
        total += (int)__popcll(mask);
    }
    __syncthreads();

    const float x = nx[lane], y = ny[lane], z = nz[lane];

    float h0[64];
#pragma unroll
    for (int j = 0; j < 64; ++j) {
        float a = fmaf(x, w0[j], fmaf(y, w0[64 + j], fmaf(z, w0[128 + j], b0[j])));
        h0[j] = fmaxf(a, 0.0f);
    }

    float h1[64];
#pragma unroll
    for (int jb = 0; jb < 4; ++jb) {
        float acc[16];
#pragma unroll
        for (int i = 0; i < 16; ++i) acc[i] = b1[jb * 16 + i];
#pragma unroll
        for (int k = 0; k < 64; ++k) {
#pragma unroll
            for (int i = 0; i < 16; ++i)
                acc[i] = fmaf(h0[k], w1[k * 64 + jb * 16 + i], acc[i]);
        }
#pragma unroll
        for (int i = 0; i < 16; ++i) h1[jb * 16 + i] = fmaxf(acc[i], 0.0f);
    }

#pragma unroll
    for (int jb = 0; jb < 8; ++jb) {
        float acc[16];
#pragma unroll
        for (int i = 0; i < 16; ++i) acc[i] = b2[jb * 16 + i];
#pragma unroll
        for (int k = 0; k < 64; ++k) {
#pragma unroll
            for (int i = 0; i < 16; ++i)
                acc[i] = fmaf(h1[k], w2[k * 128 + jb * 16 + i], acc[i]);
        }
#pragma unroll
        for (int i = 0; i < 16; ++i) {
            float v = fmaxf(acc[i], 0.0f);
            acc[i] = wave_fmax_nonneg(v);
        }
        if (lane == 63) {
#pragma unroll
            for (int i = 0; i < 16; ++i) orow[3 + jb * 16 + i] = acc[i];
        }
    }
}

extern "C" void kernel_launch(void* const* d_in, const int* in_sizes, int n_in,
                              void* d_out, int out_size, void* d_ws, size_t ws_size,
                              hipStream_t stream)
{
    (void)in_sizes; (void)n_in; (void)out_size;
    const float* pts = (const float*)d_in[0];
    const float* w0  = (const float*)d_in[1];
    const float* b0  = (const float*)d_in[2];
    const float* w1  = (const float*)d_in[3];
    const float* b1  = (const float*)d_in[4];
    const float* w2  = (const float*)d_in[5];
    const float* b2  = (const float*)d_in[6];
    float* out = (float*)d_out;

    hipLaunchKernelGGL(fps_kernel, dim3(BATCH), dim3(FPS_T), 0, stream, pts, out);

    if (ws_size >= 49152) {
        unsigned short* wsp = (unsigned short*)d_ws;
        hipLaunchKernelGGL(prep_kernel, dim3(6), dim3(256), 0, stream, w1, w2, wsp);
        hipLaunchKernelGGL(bqmlp_mfma, dim3(BATCH * KSAMP), dim3(64), 0, stream,
                           pts, w0, b0, b1, b2, wsp, out);
    } else {
        hipLaunchKernelGGL(bqmlp_fp32, dim3(BATCH * KSAMP), dim3(64), 0, stream,
                           pts, w0, b0, w1, b1, w2, b2, out);
    }
}